// Round 2
// baseline (181.071 us; speedup 1.0000x reference)
//
#include <hip/hip_runtime.h>
#include <math.h>

#define NB 16
#define NC 64
#define NT 4096
#define NDEC 128

// alpha = exp(-1/5) in fp64, rounded to fp32 (matches reference numerics)
#define ALPHA_F 0.81873075307798185867f
#define ONEMA_F 0.18126924692201814133f
// alpha^16 = exp(-3.2)
#define Q16_F   0.040762203978366216f

// Fused: conv + LIF scan per (b,c) block; last-arriving block computes the
// MLP head (tail-block pattern, device-scope release/acquire).
// out layout: [pred 1024 | true_lat 1024 | act 1024 | dd 16M]
__global__ __launch_bounds__(256) void conv_lif_fused(
    const float* __restrict__ x,
    const float* __restrict__ w3, const float* __restrict__ b3,
    const float* __restrict__ w5, const float* __restrict__ b5,
    const float* __restrict__ rw, const float* __restrict__ rb,
    const float* __restrict__ lat_scale,
    const float* __restrict__ og,
    const float* __restrict__ w1, const float* __restrict__ b1,
    const float* __restrict__ w2, const float* __restrict__ b2,
    float* __restrict__ out, int* __restrict__ counter)
{
    // layout: s_x[4104] | s_sum[4352] | s_scan[256] | wmin[4]
    // head phase aliases smem[0..4096): act[1024] mixed[1024] h[2048]
    __shared__ __align__(16) float smem[4104 + 4352 + 256 + 4];
    __shared__ int s_is_last;
    float* s_x    = smem;           // 4 zero-pad | 4096 | 4 zero-pad
    float* s_sum  = smem + 4104;    // +1 pad per 16 elements
    float* s_scan = smem + 8456;
    int*   s_wmin = (int*)(smem + 8712);

    const int bc  = blockIdx.x;
    const int c   = bc & (NC - 1);
    const int tid = threadIdx.x;

    // ---- stage x row into LDS (float4, coalesced) ----
    if (tid < 4) { s_x[tid] = 0.f; s_x[4 + NT + tid] = 0.f; }
    {
        const float4* x4  = (const float4*)(x + (size_t)bc * NT);
        float4*       sx4 = (float4*)(s_x + 4);
        #pragma unroll
        for (int i = 0; i < 4; ++i) sx4[i * 256 + tid] = x4[i * 256 + tid];
    }

    // ---- per-channel weights (block-uniform scalar loads) ----
    const float w30a = w3[(c*2+0)*3+0], w30b = w3[(c*2+0)*3+1], w30c = w3[(c*2+0)*3+2];
    const float w31a = w3[(c*2+1)*3+0], w31b = w3[(c*2+1)*3+1], w31c = w3[(c*2+1)*3+2];
    const float b30 = b3[c*2+0], b31 = b3[c*2+1];
    const float* w50p = w5 + (c*2+0)*5;
    const float* w51p = w5 + (c*2+1)*5;
    const float w50a=w50p[0], w50b=w50p[1], w50c=w50p[2], w50d=w50p[3], w50e=w50p[4];
    const float w51a=w51p[0], w51b=w51p[1], w51c=w51p[2], w51d=w51p[3], w51e=w51p[4];
    const float b50 = b5[c*2+0], b51 = b5[c*2+1];
    const float rw0 = rw[c*4+0], rw1 = rw[c*4+1], rw2 = rw[c*4+2], rw3 = rw[c*4+3];
    const float rbc = rb[c];

    __syncthreads();

    // ---- phase A: convs; dd nontemporal stores (coalesced strided-t);
    //      reduced sum -> LDS ----
    float* dd = out + 3072 + (size_t)bc * (4 * NT);
    #pragma unroll 4
    for (int i = 0; i < 16; ++i) {
        int t = i * 256 + tid;
        float xm2 = s_x[t + 2];
        float xm1 = s_x[t + 3];
        float x0  = s_x[t + 4];
        float xp1 = s_x[t + 5];
        float xp2 = s_x[t + 6];
        float o30 = fmaf(w30c, xp1, fmaf(w30b, x0, fmaf(w30a, xm1, b30)));
        float o31 = fmaf(w31c, xp1, fmaf(w31b, x0, fmaf(w31a, xm1, b31)));
        float o50 = fmaf(w50e, xp2, fmaf(w50d, xp1, fmaf(w50c, x0,
                    fmaf(w50b, xm1, fmaf(w50a, xm2, b50)))));
        float o51 = fmaf(w51e, xp2, fmaf(w51d, xp1, fmaf(w51c, x0,
                    fmaf(w51b, xm1, fmaf(w51a, xm2, b51)))));
        __builtin_nontemporal_store(o30, dd + t);
        __builtin_nontemporal_store(o31, dd + NT + t);
        __builtin_nontemporal_store(o50, dd + 2 * NT + t);
        __builtin_nontemporal_store(o51, dd + 3 * NT + t);
        s_sum[t + (t >> 4)] = fmaf(rw3, o51, fmaf(rw2, o50,
                              fmaf(rw1, o31, fmaf(rw0, o30, rbc))));
    }
    __syncthreads();

    // ---- phase B: LIF scan. thread owns t in [tid*16, tid*16+16) ----
    const int t0 = tid * 16;
    float dv[16];
    #pragma unroll
    for (int j = 0; j < 16; ++j) dv[j] = s_sum[t0 + tid + j];  // padded index

    float V = 0.f;
    #pragma unroll
    for (int j = 0; j < 16; ++j)
        V = __fadd_rn(__fmul_rn(ALPHA_F, V), __fmul_rn(ONEMA_F, dv[j]));
    s_scan[tid] = V;
    __syncthreads();

    // Kogge-Stone inclusive scan with segment coefficient q = alpha^16
    float coef = Q16_F;
    for (int off = 1; off < 256; off <<= 1) {
        float prev = (tid >= off) ? s_scan[tid - off] : 0.f;
        __syncthreads();
        s_scan[tid] = fmaf(coef, prev, s_scan[tid]);
        __syncthreads();
        coef *= coef;   // underflows to 0 after ~5 rounds; harmless
    }

    // re-run segment from exclusive prefix; first threshold crossing
    V = (tid == 0) ? 0.f : s_scan[tid - 1];
    int firstt = NT;
    #pragma unroll
    for (int j = 0; j < 16; ++j) {
        V = __fadd_rn(__fmul_rn(ALPHA_F, V), __fmul_rn(ONEMA_F, dv[j]));
        if (V >= 1.0f && firstt == NT) firstt = t0 + j;
    }

    int m = firstt;
    #pragma unroll
    for (int off = 32; off > 0; off >>= 1) m = min(m, __shfl_down(m, off));
    if ((tid & 63) == 0) s_wmin[tid >> 6] = m;
    __syncthreads();
    if (tid == 0) {
        int r = min(min(s_wmin[0], s_wmin[1]), min(s_wmin[2], s_wmin[3]));
        out[1024 + bc] = (float)r;          // true_latency
        __threadfence();                    // release: true_lat visible device-wide
        int prev = atomicAdd(counter, 1);
        s_is_last = (prev == (int)gridDim.x - 1);
    }
    __syncthreads();
    if (!s_is_last) return;

    // ================= tail block: MLP head for all 16 batches =============
    __threadfence();                        // acquire
    float* s_act   = smem;                  // alias (phase A/B done)
    float* s_mixed = smem + 1024;
    float* s_h     = smem + 2048;           // 2048 floats

    const float scale = fmaxf(lat_scale[0], 0.001f);

    #pragma unroll
    for (int k = tid; k < 1024; k += 256) {
        float tl = out[1024 + k];
        float a  = expf(-tl / scale);
        s_act[k] = a;
        out[2048 + k] = a;                  // act output
    }
    __syncthreads();

    #pragma unroll
    for (int k = tid; k < 1024; k += 256) { // mixed = act @ og^T
        int b = k >> 6, cc0 = k & 63;
        const float* ob = og + cc0 * NC;
        const float* ab = s_act + b * NC;
        float mx = 0.f;
        #pragma unroll 8
        for (int cc = 0; cc < NC; ++cc) mx = fmaf(ab[cc], ob[cc], mx);
        s_mixed[k] = mx;
    }
    __syncthreads();

    #pragma unroll
    for (int k = tid; k < 2048; k += 256) { // h = relu(mixed @ w1^T + b1)
        int b = k >> 7, j = k & 127;
        const float* mb = s_mixed + b * NC;
        const float* wj = w1 + j * NC;
        float h = b1[j];
        #pragma unroll 8
        for (int i = 0; i < NC; ++i) h = fmaf(mb[i], wj[i], h);
        s_h[k] = fmaxf(h, 0.f);
    }
    __syncthreads();

    #pragma unroll
    for (int k = tid; k < 1024; k += 256) { // pred = clip(softplus(h @ w2^T + b2))
        int b = k >> 6, cc0 = k & 63;
        const float* hb = s_h + b * NDEC;
        const float* wc = w2 + cc0 * NDEC;
        float r = b2[cc0];
        #pragma unroll 8
        for (int j = 0; j < NDEC; ++j) r = fmaf(hb[j], wc[j], r);
        float sp = fmaxf(r, 0.f) + log1pf(expf(-fabsf(r)));
        out[k] = fminf(sp, (float)NT);
    }
}

extern "C" void kernel_launch(void* const* d_in, const int* in_sizes, int n_in,
                              void* d_out, int out_size, void* d_ws, size_t ws_size,
                              hipStream_t stream) {
    const float* x  = (const float*)d_in[0];
    const float* w3 = (const float*)d_in[1];
    const float* b3 = (const float*)d_in[2];
    const float* w5 = (const float*)d_in[3];
    const float* b5 = (const float*)d_in[4];
    const float* rw = (const float*)d_in[5];
    const float* rb = (const float*)d_in[6];
    const float* ls = (const float*)d_in[7];
    const float* og = (const float*)d_in[8];
    const float* w1 = (const float*)d_in[9];
    const float* b1 = (const float*)d_in[10];
    const float* w2 = (const float*)d_in[11];
    const float* b2 = (const float*)d_in[12];
    float* out = (float*)d_out;
    int* counter = (int*)d_ws;

    hipMemsetAsync(counter, 0, sizeof(int), stream);   // graph-capturable memset node
    conv_lif_fused<<<NB * NC, 256, 0, stream>>>(
        x, w3, b3, w5, b5, rw, rb, ls, og, w1, b1, w2, b2, out, counter);
}

// Round 3
// 114.678 us; speedup vs baseline: 1.5789x; 1.5789x over previous
//
#include <hip/hip_runtime.h>
#include <math.h>

#define NB 16
#define NC 64
#define NT 4096
#define NDEC 128

// alpha = exp(-1/5) in fp64, rounded to fp32 (matches reference numerics)
#define ALPHA_F 0.81873075307798185867f
#define ONEMA_F 0.18126924692201814133f
// alpha^16 = exp(-3.2)
#define Q16_F   0.040762203978366216f

// One block per (b,c). Phase A: convs with float4 dd stores (1 KB/wave-instr,
// full-line). Phase B: LIF linear-recurrence scan (16/thread + Kogge-Stone).
// out layout: [pred 1024 | true_lat 1024 | act 1024 | dd 16M]
__global__ __launch_bounds__(256) void conv_lif_kernel(
    const float* __restrict__ x,
    const float* __restrict__ w3, const float* __restrict__ b3,
    const float* __restrict__ w5, const float* __restrict__ b5,
    const float* __restrict__ rw, const float* __restrict__ rb,
    float* __restrict__ out)
{
    __shared__ __align__(16) float s_x[4 + NT + 4];   // x[-4..-1]=0 | x | x[T..T+3]=0
    __shared__ float s_sum[NT + 256];                 // +1 pad per 16 floats
    __shared__ float s_scan[256];
    __shared__ int   s_wmin[4];

    const int bc  = blockIdx.x;
    const int c   = bc & (NC - 1);
    const int tid = threadIdx.x;

    // ---- stage x row into LDS (float4, coalesced) ----
    if (tid < 4) { s_x[tid] = 0.f; s_x[4 + NT + tid] = 0.f; }
    {
        const float4* x4  = (const float4*)(x + (size_t)bc * NT);
        float4*       sx4 = (float4*)(s_x + 4);
        #pragma unroll
        for (int i = 0; i < 4; ++i) sx4[i * 256 + tid] = x4[i * 256 + tid];
    }

    // ---- per-channel weights (block-uniform scalar loads) ----
    const float w30a = w3[(c*2+0)*3+0], w30b = w3[(c*2+0)*3+1], w30c = w3[(c*2+0)*3+2];
    const float w31a = w3[(c*2+1)*3+0], w31b = w3[(c*2+1)*3+1], w31c = w3[(c*2+1)*3+2];
    const float b30 = b3[c*2+0], b31 = b3[c*2+1];
    const float* w50p = w5 + (c*2+0)*5;
    const float* w51p = w5 + (c*2+1)*5;
    const float w50a=w50p[0], w50b=w50p[1], w50c=w50p[2], w50d=w50p[3], w50e=w50p[4];
    const float w51a=w51p[0], w51b=w51p[1], w51c=w51p[2], w51d=w51p[3], w51e=w51p[4];
    const float b50 = b5[c*2+0], b51 = b5[c*2+1];
    const float rw0 = rw[c*4+0], rw1 = rw[c*4+1], rw2 = rw[c*4+2], rw3 = rw[c*4+3];
    const float rbc = rb[c];

    __syncthreads();

    // ---- phase A: convs; float4 dd stores; reduced sum -> padded LDS ----
    float* dd = out + 3072 + (size_t)bc * (4 * NT);
    #pragma unroll
    for (int i = 0; i < 4; ++i) {
        const int t = i * 1024 + tid * 4;          // 4 consecutive outputs
        // aligned ds_read_b128 x3: covers x[t-4 .. t+7]
        const float4 c0 = *(const float4*)(s_x + t);       // x[t-4..t-1]
        const float4 c1 = *(const float4*)(s_x + t + 4);   // x[t..t+3]
        const float4 c2 = *(const float4*)(s_x + t + 8);   // x[t+4..t+7]
        const float in[8] = {c0.z, c0.w, c1.x, c1.y, c1.z, c1.w, c2.x, c2.y};
        float4 v30, v31, v50, v51;
        const int pad = t >> 4;                    // same pad block for j=0..3
        #pragma unroll
        for (int j = 0; j < 4; ++j) {
            const float xm2 = in[j], xm1 = in[j+1], x0 = in[j+2];
            const float xp1 = in[j+3], xp2 = in[j+4];
            float o30 = fmaf(w30c, xp1, fmaf(w30b, x0, fmaf(w30a, xm1, b30)));
            float o31 = fmaf(w31c, xp1, fmaf(w31b, x0, fmaf(w31a, xm1, b31)));
            float o50 = fmaf(w50e, xp2, fmaf(w50d, xp1, fmaf(w50c, x0,
                        fmaf(w50b, xm1, fmaf(w50a, xm2, b50)))));
            float o51 = fmaf(w51e, xp2, fmaf(w51d, xp1, fmaf(w51c, x0,
                        fmaf(w51b, xm1, fmaf(w51a, xm2, b51)))));
            ((float*)&v30)[j] = o30;
            ((float*)&v31)[j] = o31;
            ((float*)&v50)[j] = o50;
            ((float*)&v51)[j] = o51;
            s_sum[t + j + pad] = fmaf(rw3, o51, fmaf(rw2, o50,
                                 fmaf(rw1, o31, fmaf(rw0, o30, rbc))));
        }
        *(float4*)(dd + t)          = v30;
        *(float4*)(dd + NT + t)     = v31;
        *(float4*)(dd + 2 * NT + t) = v50;
        *(float4*)(dd + 3 * NT + t) = v51;
    }
    __syncthreads();

    // ---- phase B: LIF scan. thread owns t in [tid*16, tid*16+16) ----
    const int t0 = tid * 16;
    float dv[16];
    #pragma unroll
    for (int j = 0; j < 16; ++j) dv[j] = s_sum[t0 + tid + j];  // padded index

    float V = 0.f;
    #pragma unroll
    for (int j = 0; j < 16; ++j)
        V = __fadd_rn(__fmul_rn(ALPHA_F, V), __fmul_rn(ONEMA_F, dv[j]));
    s_scan[tid] = V;
    __syncthreads();

    // Kogge-Stone inclusive scan with segment coefficient q = alpha^16
    float coef = Q16_F;
    for (int off = 1; off < 256; off <<= 1) {
        float prev = (tid >= off) ? s_scan[tid - off] : 0.f;
        __syncthreads();
        s_scan[tid] = fmaf(coef, prev, s_scan[tid]);
        __syncthreads();
        coef *= coef;   // underflows to 0 after ~5 rounds; harmless
    }

    // re-run segment from exclusive prefix; first threshold crossing
    float V2 = (tid == 0) ? 0.f : s_scan[tid - 1];
    int firstt = NT;
    #pragma unroll
    for (int j = 0; j < 16; ++j) {
        V2 = __fadd_rn(__fmul_rn(ALPHA_F, V2), __fmul_rn(ONEMA_F, dv[j]));
        if (V2 >= 1.0f && firstt == NT) firstt = t0 + j;
    }

    int m = firstt;
    #pragma unroll
    for (int off = 32; off > 0; off >>= 1) m = min(m, __shfl_down(m, off));
    if ((tid & 63) == 0) s_wmin[tid >> 6] = m;
    __syncthreads();
    if (tid == 0) {
        int r = min(min(s_wmin[0], s_wmin[1]), min(s_wmin[2], s_wmin[3]));
        out[1024 + bc] = (float)r;   // true_latency (T if never fired)
    }
}

// One block per batch element: act -> gates -> MLP -> softplus/clip
__global__ __launch_bounds__(128) void head_kernel(
    const float* __restrict__ lat_scale,
    const float* __restrict__ og,
    const float* __restrict__ w1, const float* __restrict__ b1,
    const float* __restrict__ w2, const float* __restrict__ b2,
    float* __restrict__ out)
{
    __shared__ float act_s[NC];
    __shared__ float mixed_s[NC];
    __shared__ float h_s[NDEC];
    const int b   = blockIdx.x;
    const int tid = threadIdx.x;
    const float scale = fmaxf(lat_scale[0], 0.001f);

    if (tid < NC) {
        float tl = out[1024 + b * NC + tid];
        float a  = expf(-tl / scale);
        act_s[tid] = a;
        out[2048 + b * NC + tid] = a;        // act output
    }
    __syncthreads();

    if (tid < NC) {
        float mx = 0.f;
        #pragma unroll 8
        for (int cc = 0; cc < NC; ++cc) mx = fmaf(act_s[cc], og[tid * NC + cc], mx);
        mixed_s[tid] = mx;
    }
    __syncthreads();

    {   // all 128 threads: hidden layer
        float h = b1[tid];
        #pragma unroll 8
        for (int i = 0; i < NC; ++i) h = fmaf(mixed_s[i], w1[tid * NC + i], h);
        h_s[tid] = fmaxf(h, 0.f);
    }
    __syncthreads();

    if (tid < NC) {
        float r = b2[tid];
        #pragma unroll 8
        for (int j = 0; j < NDEC; ++j) r = fmaf(h_s[j], w2[tid * NDEC + j], r);
        float sp = fmaxf(r, 0.f) + log1pf(expf(-fabsf(r)));
        out[b * NC + tid] = fminf(sp, (float)NT);
    }
}

extern "C" void kernel_launch(void* const* d_in, const int* in_sizes, int n_in,
                              void* d_out, int out_size, void* d_ws, size_t ws_size,
                              hipStream_t stream) {
    const float* x  = (const float*)d_in[0];
    const float* w3 = (const float*)d_in[1];
    const float* b3 = (const float*)d_in[2];
    const float* w5 = (const float*)d_in[3];
    const float* b5 = (const float*)d_in[4];
    const float* rw = (const float*)d_in[5];
    const float* rb = (const float*)d_in[6];
    const float* ls = (const float*)d_in[7];
    const float* og = (const float*)d_in[8];
    const float* w1 = (const float*)d_in[9];
    const float* b1 = (const float*)d_in[10];
    const float* w2 = (const float*)d_in[11];
    const float* b2 = (const float*)d_in[12];
    float* out = (float*)d_out;

    conv_lif_kernel<<<NB * NC, 256, 0, stream>>>(x, w3, b3, w5, b5, rw, rb, out);
    head_kernel<<<NB, 128, 0, stream>>>(ls, og, w1, b1, w2, b2, out);
}

// Round 4
// 113.891 us; speedup vs baseline: 1.5899x; 1.0069x over previous
//
#include <hip/hip_runtime.h>
#include <math.h>

#define NB 16
#define NC 64
#define NT 4096
#define NDEC 128

// alpha = exp(-1/5) in fp64, rounded to fp32 (matches reference numerics)
#define ALPHA_F 0.81873075307798185867f
#define ONEMA_F 0.18126924692201814133f
// alpha^16 = exp(-3.2)  (per-thread-segment decay)
#define Q16_F   0.040762203978366216f

// Barrier that waits LDS ops only — deliberately does NOT drain vmcnt, so
// in-flight dd global stores keep draining across the scan phase.
#define LGKM_BARRIER() asm volatile("s_waitcnt lgkmcnt(0)\n\ts_barrier" ::: "memory")

// One block per (b,c). Phase A: convs + float4 dd stores (full-line, coalesced).
// Phase B: LIF scan — 16 steps/thread, 5-round wave shuffle-scan, single
// cross-wave carry (q^64 == 0 in fp32 => only previous wave matters).
// out layout: [pred 1024 | true_lat 1024 | act 1024 | dd 16M]
__global__ __launch_bounds__(256) void conv_lif_kernel(
    const float* __restrict__ x,
    const float* __restrict__ w3, const float* __restrict__ b3,
    const float* __restrict__ w5, const float* __restrict__ b5,
    const float* __restrict__ rw, const float* __restrict__ rb,
    float* __restrict__ out)
{
    __shared__ __align__(16) float s_x[4 + NT + 4];   // zero pad 4 each side
    __shared__ float s_sum[NT + 256];                 // +1 pad per 16 floats
    __shared__ float s_part[4];
    __shared__ int   s_wmin[4];

    const int bc  = blockIdx.x;
    const int c   = bc & (NC - 1);
    const int tid = threadIdx.x;
    const int lane = tid & 63;

    // ---- stage x row into LDS (float4, coalesced) ----
    if (tid < 4) { s_x[tid] = 0.f; s_x[4 + NT + tid] = 0.f; }
    {
        const float4* x4  = (const float4*)(x + (size_t)bc * NT);
        float4*       sx4 = (float4*)(s_x + 4);
        #pragma unroll
        for (int i = 0; i < 4; ++i) sx4[i * 256 + tid] = x4[i * 256 + tid];
    }

    // ---- per-channel weights (block-uniform scalar loads) ----
    const float w30a = w3[(c*2+0)*3+0], w30b = w3[(c*2+0)*3+1], w30c = w3[(c*2+0)*3+2];
    const float w31a = w3[(c*2+1)*3+0], w31b = w3[(c*2+1)*3+1], w31c = w3[(c*2+1)*3+2];
    const float b30 = b3[c*2+0], b31 = b3[c*2+1];
    const float* w50p = w5 + (c*2+0)*5;
    const float* w51p = w5 + (c*2+1)*5;
    const float w50a=w50p[0], w50b=w50p[1], w50c=w50p[2], w50d=w50p[3], w50e=w50p[4];
    const float w51a=w51p[0], w51b=w51p[1], w51c=w51p[2], w51d=w51p[3], w51e=w51p[4];
    const float b50 = b5[c*2+0], b51 = b5[c*2+1];
    const float rw0 = rw[c*4+0], rw1 = rw[c*4+1], rw2 = rw[c*4+2], rw3 = rw[c*4+3];
    const float rbc = rb[c];

    __syncthreads();   // staging: needs the global->LDS writes visible

    // ---- phase A: convs; float4 dd stores; reduced sum -> padded LDS ----
    float* dd = out + 3072 + (size_t)bc * (4 * NT);
    #pragma unroll
    for (int i = 0; i < 4; ++i) {
        const int t = i * 1024 + tid * 4;          // 4 consecutive outputs
        const float4 c0 = *(const float4*)(s_x + t);       // x[t-4..t-1]
        const float4 c1 = *(const float4*)(s_x + t + 4);   // x[t..t+3]
        const float4 c2 = *(const float4*)(s_x + t + 8);   // x[t+4..t+7]
        const float in[8] = {c0.z, c0.w, c1.x, c1.y, c1.z, c1.w, c2.x, c2.y};
        float4 v30, v31, v50, v51;
        const int pad = t >> 4;                    // same pad block for j=0..3
        #pragma unroll
        for (int j = 0; j < 4; ++j) {
            const float xm2 = in[j], xm1 = in[j+1], x0 = in[j+2];
            const float xp1 = in[j+3], xp2 = in[j+4];
            float o30 = fmaf(w30c, xp1, fmaf(w30b, x0, fmaf(w30a, xm1, b30)));
            float o31 = fmaf(w31c, xp1, fmaf(w31b, x0, fmaf(w31a, xm1, b31)));
            float o50 = fmaf(w50e, xp2, fmaf(w50d, xp1, fmaf(w50c, x0,
                        fmaf(w50b, xm1, fmaf(w50a, xm2, b50)))));
            float o51 = fmaf(w51e, xp2, fmaf(w51d, xp1, fmaf(w51c, x0,
                        fmaf(w51b, xm1, fmaf(w51a, xm2, b51)))));
            ((float*)&v30)[j] = o30;
            ((float*)&v31)[j] = o31;
            ((float*)&v50)[j] = o50;
            ((float*)&v51)[j] = o51;
            s_sum[t + j + pad] = fmaf(rw3, o51, fmaf(rw2, o50,
                                 fmaf(rw1, o31, fmaf(rw0, o30, rbc))));
        }
        *(float4*)(dd + t)          = v30;
        *(float4*)(dd + NT + t)     = v31;
        *(float4*)(dd + 2 * NT + t) = v50;
        *(float4*)(dd + 3 * NT + t) = v51;
    }
    // only s_sum needs protecting — let dd stores stay in flight
    LGKM_BARRIER();

    // ---- phase B: LIF scan. thread owns t in [tid*16, tid*16+16) ----
    const int t0 = tid * 16;
    float dv[16];
    #pragma unroll
    for (int j = 0; j < 16; ++j) dv[j] = s_sum[t0 + tid + j];  // padded index

    // segment result B_tid (affine map applied to 0)
    float V = 0.f;
    #pragma unroll
    for (int j = 0; j < 16; ++j)
        V = __fadd_rn(__fmul_rn(ALPHA_F, V), __fmul_rn(ONEMA_F, dv[j]));

    // wave-level inclusive scan, coefficient q = alpha^16.
    // q^32 == 0 in fp32, so offsets >= 32 contribute nothing: 5 rounds.
    float S = V;
    float coef = Q16_F;
    #pragma unroll
    for (int off = 1; off <= 16; off <<= 1) {
        float p = __shfl_up(S, off);
        if (lane >= off) S = fmaf(coef, p, S);
        coef *= coef;
    }

    // cross-wave carry: q^64 == 0 => only previous wave's partial matters
    if (lane == 63) s_part[tid >> 6] = S;
    LGKM_BARRIER();
    const float Pprev = (tid >= 64) ? s_part[(tid >> 6) - 1] : 0.f;

    // q^lane via exact repeated squaring
    float ql = 1.f, qp = Q16_F;
    #pragma unroll
    for (int bit = 0; bit < 6; ++bit) {
        if ((lane >> bit) & 1) ql *= qp;
        qp *= qp;
    }

    // exclusive prefix for this thread, then re-run for first crossing
    float Sm1 = __shfl_up(S, 1);
    float V2 = fmaf(Pprev, ql, (lane > 0) ? Sm1 : 0.f);
    int firstt = NT;
    #pragma unroll
    for (int j = 0; j < 16; ++j) {
        V2 = __fadd_rn(__fmul_rn(ALPHA_F, V2), __fmul_rn(ONEMA_F, dv[j]));
        if (V2 >= 1.0f && firstt == NT) firstt = t0 + j;
    }

    int m = firstt;
    #pragma unroll
    for (int off = 32; off > 0; off >>= 1) m = min(m, __shfl_down(m, off));
    if (lane == 0) s_wmin[tid >> 6] = m;
    LGKM_BARRIER();
    if (tid == 0) {
        int r = min(min(s_wmin[0], s_wmin[1]), min(s_wmin[2], s_wmin[3]));
        out[1024 + bc] = (float)r;   // true_latency (T if never fired)
    }
    // end-of-kernel implicit wait drains the dd stores (overlapped with phase B)
}

// One block per batch element: act -> gates -> MLP -> softplus/clip
__global__ __launch_bounds__(128) void head_kernel(
    const float* __restrict__ lat_scale,
    const float* __restrict__ og,
    const float* __restrict__ w1, const float* __restrict__ b1,
    const float* __restrict__ w2, const float* __restrict__ b2,
    float* __restrict__ out)
{
    __shared__ float act_s[NC];
    __shared__ float mixed_s[NC];
    __shared__ float h_s[NDEC];
    const int b   = blockIdx.x;
    const int tid = threadIdx.x;
    const float scale = fmaxf(lat_scale[0], 0.001f);

    if (tid < NC) {
        float tl = out[1024 + b * NC + tid];
        float a  = expf(-tl / scale);
        act_s[tid] = a;
        out[2048 + b * NC + tid] = a;        // act output
    }
    __syncthreads();

    if (tid < NC) {
        float mx = 0.f;
        #pragma unroll 8
        for (int cc = 0; cc < NC; ++cc) mx = fmaf(act_s[cc], og[tid * NC + cc], mx);
        mixed_s[tid] = mx;
    }
    __syncthreads();

    {   // all 128 threads: hidden layer
        float h = b1[tid];
        #pragma unroll 8
        for (int i = 0; i < NC; ++i) h = fmaf(mixed_s[i], w1[tid * NC + i], h);
        h_s[tid] = fmaxf(h, 0.f);
    }
    __syncthreads();

    if (tid < NC) {
        float r = b2[tid];
        #pragma unroll 8
        for (int j = 0; j < NDEC; ++j) r = fmaf(h_s[j], w2[tid * NDEC + j], r);
        float sp = fmaxf(r, 0.f) + log1pf(expf(-fabsf(r)));
        out[b * NC + tid] = fminf(sp, (float)NT);
    }
}

extern "C" void kernel_launch(void* const* d_in, const int* in_sizes, int n_in,
                              void* d_out, int out_size, void* d_ws, size_t ws_size,
                              hipStream_t stream) {
    const float* x  = (const float*)d_in[0];
    const float* w3 = (const float*)d_in[1];
    const float* b3 = (const float*)d_in[2];
    const float* w5 = (const float*)d_in[3];
    const float* b5 = (const float*)d_in[4];
    const float* rw = (const float*)d_in[5];
    const float* rb = (const float*)d_in[6];
    const float* ls = (const float*)d_in[7];
    const float* og = (const float*)d_in[8];
    const float* w1 = (const float*)d_in[9];
    const float* b1 = (const float*)d_in[10];
    const float* w2 = (const float*)d_in[11];
    const float* b2 = (const float*)d_in[12];
    float* out = (float*)d_out;

    conv_lif_kernel<<<NB * NC, 256, 0, stream>>>(x, w3, b3, w5, b5, rw, rb, out);
    head_kernel<<<NB, 128, 0, stream>>>(ls, og, w1, b1, w2, b2, out);
}